// Round 4
// baseline (349.530 us; speedup 1.0000x reference)
//
#include <hip/hip_runtime.h>
#include <hip/hip_fp16.h>
#include <cstddef>

#define Bc   32
#define Nc   512
#define Mc   512
#define DFc  64
#define BIGC 1.0e10f
#define LOG2E_F 1.4426950408889634f
#define LN2_F   0.6931471805599453f

typedef unsigned int uint32;

// lane l gets lane l-1's src; lane 0 gets `oldv`  (DPP wave_shr:1)
__device__ __forceinline__ float dpp_shr1(float oldv, float src) {
    return __int_as_float(__builtin_amdgcn_update_dpp(
        __float_as_int(oldv), __float_as_int(src), 0x138, 0xf, 0xf, false));
}

// ---------------------------------------------------------------------------
// Kernel 1: distances in SCALED (x LOG2E) fp16, packed for the r=2 scan:
//   tile = (b*4 + strip)*8 + J   (strip = 128-row band, J = 64-col band)
//   dword [gi*256 + l*4 + e] (i.e. uint4 [gi*64+l], component e):
//     half2( D[128*strip + 2l][64J + c], D[128*strip + 2l + 1][64J + c] )*LOG2E
//   where c = 4*gi + e - l  (clamped garbage outside [0,64) — never consumed).
// Block: 256 threads computes a 128(row)x64(col) slab = 1 scan tile.
// ---------------------------------------------------------------------------
__global__ __launch_bounds__(256) void dist_kernel(
    const float* __restrict__ X, const float* __restrict__ Y,
    uint32* __restrict__ Dsk)
{
    __shared__ __align__(16) float Xs[128][68];
    __shared__ __align__(16) float Ys[64][68];

    const int b  = blockIdx.z;
    const int n0 = blockIdx.y * 128;
    const int m0 = blockIdx.x * 64;
    const int tid = threadIdx.x;

    const float* Xg = X + ((size_t)b * Nc + n0) * DFc;
    const float* Yg = Y + ((size_t)b * Mc + m0) * DFc;

    // X rows stored k-rotated by 4*n (mod 64) to spread xv gather banks.
#pragma unroll
    for (int it = 0; it < 8; ++it) {
        int e4 = it * 256 + tid;
        int n = e4 >> 4, k = (e4 & 15) * 4;
        *(float4*)&Xs[n][(k + 4 * n) & 63] = *(const float4*)&Xg[e4 * 4];
    }
#pragma unroll
    for (int it = 0; it < 4; ++it) {
        int e4 = it * 256 + tid;
        int n = e4 >> 4, k = (e4 & 15) * 4;
        *(float4*)&Ys[n][k] = *(const float4*)&Yg[e4 * 4];
    }
    __syncthreads();

    const int tx = tid & 15;
    const int ty = tid >> 4;

    float acc[8][4];
#pragma unroll
    for (int a = 0; a < 8; ++a)
#pragma unroll
        for (int c = 0; c < 4; ++c) acc[a][c] = 0.0f;

#pragma unroll
    for (int k4 = 0; k4 < 16; ++k4) {
        float4 xv[8], yv[4];
#pragma unroll
        for (int a = 0; a < 8; ++a) {
            int r = ty + 16 * a;
            xv[a] = *(const float4*)&Xs[r][(k4 * 4 + 4 * r) & 63];
        }
#pragma unroll
        for (int c = 0; c < 4; ++c)
            yv[c] = *(const float4*)&Ys[tx + 16 * c][k4 * 4];
#pragma unroll
        for (int a = 0; a < 8; ++a) {
#pragma unroll
            for (int c = 0; c < 4; ++c) {
                float d0 = xv[a].x - yv[c].x;
                float d1 = xv[a].y - yv[c].y;
                float d2 = xv[a].z - yv[c].z;
                float d3 = xv[a].w - yv[c].w;
                acc[a][c] = fmaf(d0, d0,
                            fmaf(d1, d1,
                            fmaf(d2, d2,
                            fmaf(d3, d3, acc[a][c]))));
            }
        }
    }
    __syncthreads();   // done reading Xs/Ys; alias Xs as Ct

    // Ct[128][66]: epilogue reads have lane addr-stride 131 -> 2-way (free)
    float* Ct = (float*)Xs;
#pragma unroll
    for (int a = 0; a < 8; ++a) {
        int r = ty + 16 * a;
#pragma unroll
        for (int c = 0; c < 4; ++c)
            Ct[r * 66 + tx + 16 * c] = acc[a][c];
    }
    __syncthreads();

    const int l = tid & 63;
    const int q = tid >> 6;   // 0..3
    uint4* outt = (uint4*)Dsk +
        (((size_t)b * 4 + blockIdx.y) * 8 + blockIdx.x) * 2048;
    const float* CrowA = Ct + (2 * l) * 66;
    const float* CrowB = Ct + (2 * l + 1) * 66;
#pragma unroll
    for (int g = 0; g < 8; ++g) {
        int gi = q + 4 * g;
        uint32 u[4];
#pragma unroll
        for (int e = 0; e < 4; ++e) {
            int c = min(max(4 * gi + e - l, 0), 63);
            __half2 h = __floats2half2_rn(CrowA[c] * LOG2E_F,
                                          CrowB[c] * LOG2E_F);
            u[e] = *(uint32*)&h;
        }
        uint4 v; v.x = u[0]; v.y = u[1]; v.z = u[2]; v.w = u[3];
        outt[gi * 64 + l] = v;
    }
}

// ---------------------------------------------------------------------------
// Kernel 2: tile-systolic soft-DTW scan, 2 rows/lane, 4 waves (1 per SIMD).
// Wave w owns DP rows 128w+1..128w+128; lane l rows a=128w+2l+1, b=a+1.
// 11 tile-steps x 128 steps; per step: one DPP + two chained softmins.
// Hold-semantics (cndmask on cur updates) carries left-column state across
// tiles in registers — no edge-injection selects. Frontier row via one
// ds_read per tile into Fv + uniform readlane per step (no LDS reads in
// the hot loop); frontier writes: single ds_write (lane63 real / dump).
// ---------------------------------------------------------------------------
__global__ __launch_bounds__(256) void scan_kernel(
    const uint32* __restrict__ Dsk,
    const int* __restrict__ X_len, const int* __restrict__ Y_len,
    float* __restrict__ out)
{
    __shared__ __align__(16) float Frow[4][516];
    __shared__ float dumpArr[132];

    const int tid = threadIdx.x;
    const int l = tid & 63;
    const int wu = __builtin_amdgcn_readfirstlane(tid >> 6);   // 0..3, scalar
    const int b = blockIdx.x;

    const int xl = X_len[b], yl = Y_len[b];
    const int wxl = (xl - 1) >> 7;           // capture wave
    const int iw  = (xl - 1) & 127;          // row-in-wave - 1
    const int lcap = iw >> 1;                // capture lane
    const int useB = iw & 1;                 // row parity: 0 -> cellA, 1 -> cellB
    const int Jcap = (yl - 1) >> 6;          // capture tile
    const int scapBase = (yl - (Jcap << 6)) + lcap;   // capture step in tile

    const bool is63 = (l == 63);

    // Persistent DP state. curA/curB: left column (held right-edge of the
    // previous tile); diagA: diag for cellA. R[0][0]=0 seeds wave0/lane0.
    float curA = BIGC, curB = BIGC;
    float diagA = (wu == 0 && l == 0) ? 0.0f : BIGC;
    float capv = 0.0f;

    for (int k = 0; k < 11; ++k) {
        int J = k - wu;
        if (0 <= J && J < 8) {
            const int j0 = J << 6;
            // frontier (row 128w) for this tile's 64 cols, one value per lane
            float Fv = BIGC;
            if (wu > 0) Fv = Frow[wu - 1][j0 + 1 + l];
            const uint4* tp = (const uint4*)Dsk +
                ((((size_t)b * 4 + wu) * 8) + J) * 2048 + l;
            int scap = (wu == wxl && J == Jcap) ? scapBase : -1000;
            float* wrbase = is63 ? (&Frow[wu][0] + (j0 - 63)) : dumpArr;

            uint4 dreg[4];
            dreg[0] = tp[0]; dreg[1] = tp[64]; dreg[2] = tp[128];

            for (int g4 = 0; g4 < 8; ++g4) {
#pragma unroll
                for (int gg = 0; gg < 4; ++gg) {
                    int gi = g4 * 4 + gg;           // 0..31 ; gi&3 == gg
                    uint4 dcur = dreg[gg];
                    int gpre = gi + 3; if (gpre > 31) gpre = 31;
                    dreg[(gg + 3) & 3] = tp[gpre * 64];
                    const uint32 du[4] = {dcur.x, dcur.y, dcur.z, dcur.w};
                    int sb = 4 * gi + 1;
#pragma unroll
                    for (int e = 0; e < 4; ++e) {
                        int s = sb + e;             // 1..128 (uniform)
                        float2 d2 = __half22float2(*(const __half2*)&du[e]);
                        int idx = s - 1; if (idx > 63) idx = 63;
                        float fs = __int_as_float(
                            __builtin_amdgcn_readlane(__float_as_int(Fv), idx));
                        float upA = dpp_shr1(fs, curB);
                        // cell A (row a): dg=diagA, up=upA, lt=curA
                        float mnA = fminf(diagA, fminf(upA, curA));
                        float eA  = exp2f(mnA - diagA) + exp2f(mnA - upA)
                                  + exp2f(mnA - curA);
                        float valA = (mnA - log2f(eA)) + d2.x;
                        // cell B (row a+1): dg=curA(old), up=valA, lt=curB
                        float mnB = fminf(curA, fminf(valA, curB));
                        float eB  = exp2f(mnB - curA) + exp2f(mnB - valA)
                                  + exp2f(mnB - curB);
                        float valB = (mnB - log2f(eB)) + d2.y;
                        // output capture (scalar compare; lane lcap's value)
                        float vsel = useB ? valB : valA;
                        capv = (s == scap) ? vsel : capv;
                        // hold-update: active window s in [l+1, l+64]
                        bool act = ((unsigned)(s - 1 - l) < 64u);
                        diagA = upA;
                        curA = act ? valA : curA;
                        curB = act ? valB : curB;
                        // frontier publish: lane63&act -> Frow[w][j0-63+s]
                        float* sp = (act ? wrbase : dumpArr) + s;
                        *sp = valB;
                    }
                }
            }
        }
        __syncthreads();
    }

    if (wu == wxl) {
        float o = __int_as_float(
            __builtin_amdgcn_readlane(__float_as_int(capv), lcap));
        if (l == 0) out[b] = o * LN2_F;
    }
}

extern "C" void kernel_launch(void* const* d_in, const int* in_sizes, int n_in,
                              void* d_out, int out_size, void* d_ws, size_t ws_size,
                              hipStream_t stream)
{
    const float* X  = (const float*)d_in[0];
    const float* Y  = (const float*)d_in[1];
    const int*   xl = (const int*)d_in[2];
    const int*   yl = (const int*)d_in[3];
    float* out = (float*)d_out;
    uint32* Dsk = (uint32*)d_ws;   // 32 b * 4 strips * 8 J * 32 KB = 32 MB

    dist_kernel<<<dim3(8, 4, Bc), 256, 0, stream>>>(X, Y, Dsk);
    scan_kernel<<<Bc, 256, 0, stream>>>(Dsk, xl, yl, out);
}